// Round 11
// baseline (191.687 us; speedup 1.0000x reference)
//
#include <hip/hip_runtime.h>
#include <hip/hip_bf16.h>
#include <stdint.h>

// Problem constants: B=2, S=2048, E=1024, H=16, hd=64.
#define SS 2048
#define EE 1024
#define HH 16
#define HD 64

// 0.125 (1/sqrt(hd)) * log2(e): scores come out of QK^T already in exp2-domain.
#define QSCALE 0.1803368801111137f

typedef __attribute__((ext_vector_type(8))) short short8;
typedef __attribute__((ext_vector_type(4))) float f32x4;
typedef __attribute__((ext_vector_type(16))) float f32x16;

__device__ __forceinline__ short f2bf(float f) {
  union { float f; uint32_t u; } x; x.f = f;
  uint32_t r = x.u + 0x7fffu + ((x.u >> 16) & 1u);
  return (short)(r >> 16);
}

__device__ __forceinline__ uint32_t pk_bf16(float a, float b) {
#if __has_builtin(__builtin_amdgcn_cvt_pk_bf16_f32)
  typedef __attribute__((ext_vector_type(2))) __bf16 bf16x2_t;
  union { bf16x2_t v; uint32_t u; } x;
  x.v = __builtin_amdgcn_cvt_pk_bf16_f32(a, b);
  return x.u;
#else
  return (uint32_t)(uint16_t)f2bf(a) | ((uint32_t)(uint16_t)f2bf(b) << 16);
#endif
}

#if __has_builtin(__builtin_amdgcn_exp2f)
#define EXP2F __builtin_amdgcn_exp2f
#else
#define EXP2F exp2f
#endif

__device__ __forceinline__ void async_cp16(const void* g, void* l) {
  __builtin_amdgcn_global_load_lds((const __attribute__((address_space(1))) void*)g,
                                   (__attribute__((address_space(3))) void*)l, 16, 0, 0);
}

// ---------------- fp32 -> bf16 pre-convert (X, W_in, W_out) ----------------
// Grid-stride at 2048 blocks (G11). Measured ~6 TB/s -> at HBM roofline.
#define N4_X  1048576
#define N4_W1 786432
#define N4_W2 262144
#define N4_ALL (N4_X + N4_W1 + N4_W2)
__global__ __launch_bounds__(256) void cvt_all(
    const float* __restrict__ x, const float* __restrict__ w1,
    const float* __restrict__ w2,
    short* __restrict__ xb, short* __restrict__ w1b, short* __restrict__ w2b)
{
  for (int i = blockIdx.x * 256 + threadIdx.x; i < N4_ALL; i += 2048 * 256) {
    const float* src; short* dst; int off;
    if (i < N4_X)            { src = x;  dst = xb;  off = i; }
    else if (i < N4_X+N4_W1) { src = w1; dst = w1b; off = i - N4_X; }
    else                     { src = w2; dst = w2b; off = i - N4_X - N4_W1; }
    float4 v = *(const float4*)&src[(size_t)off * 4];
    uint2 pk;
    pk.x = pk_bf16(v.x, v.y);
    pk.y = pk_bf16(v.z, v.w);
    *(uint2*)&dst[(size_t)off * 4] = pk;
  }
}

// ====== QKV GEMM: BM=128 x BN=128, BK=32, dbuf async global->LDS (R18 loop) ======
// Orientation branch hoisted OUT of the K-loop (R2/R3 lesson). Bias loads
// hoisted above the K-loop (R23). NO manual vmcnt/sched_barrier (R19 lesson).
// V layout NOTE (R24, matches attn 32x32 kv-split): within each 32-aligned
// s-subgroup, stored position 16f + 8h + j holds kv = 16f + 4h + (j&3) + 8*(j>>2)
// (f,h in {0,1}, j in [0,8)). At 4-block granularity this is a bit0<->bit1 swap
// of the 4-block index within each 32-group; order inside 4-blocks preserved.
__global__ __launch_bounds__(256) void gemm_qkv(
    const short* __restrict__ A, const short* __restrict__ Bw,
    const float* __restrict__ bias,
    short* __restrict__ qw, short* __restrict__ kw, short* __restrict__ vw,
    int M, int N, int K)
{
  __shared__ short smem[17408];
  const int tid = threadIdx.x;
  const int lane = tid & 63;
  const int wv = tid >> 6;
  const int wm = (wv >> 1) * 64;
  const int wn = (wv & 1) * 64;
  const int t = lane >> 4;
  const int lr = lane & 15;
  const int bm = blockIdx.y * 128;
  const int bn = blockIdx.x * 128;

  f32x4 acc[4][4];
  #pragma unroll
  for (int i = 0; i < 4; ++i)
    #pragma unroll
    for (int j = 0; j < 4; ++j) acc[i][j] = (f32x4){0.f, 0.f, 0.f, 0.f};

  auto stage = [&](int buf, int k0) {
    short* sA = smem + buf * 8192;
    short* sB = smem + buf * 8192 + 4096;
    #pragma unroll
    for (int it = 0; it < 2; ++it) {
      int c = it * 256 + wv * 64 + lane;
      int row = c >> 2;
      int ch = (c & 3) * 8;
      async_cp16(&A[(size_t)(bm + row) * K + k0 + ch],
                 (char*)sA + (size_t)(it * 256 + wv * 64) * 16);
      async_cp16(&Bw[(size_t)(bn + row) * K + k0 + ch],
                 (char*)sB + (size_t)(it * 256 + wv * 64) * 16);
    }
  };

  const bool isV = (bn >= 2048);
  const bool isQ = (bn < 1024);
  const int nk = K >> 5;
  stage(0, 0);
  __syncthreads();

  if (isV) {
    float bvv[4];
    #pragma unroll
    for (int j = 0; j < 4; ++j) bvv[j] = bias[bn + wn + j*16 + lr];

    // original orientation: lane holds 4 consecutive s (rows), col = d
    for (int k = 0; k < nk; ++k) {
      if (k + 1 < nk) stage((k + 1) & 1, (k + 1) << 5);
      const short* cA = smem + (k & 1) * 8192;
      const short* cB = smem + (k & 1) * 8192 + 4096;
      short8 af[4], bfr[4];
      #pragma unroll
      for (int i = 0; i < 4; ++i) af[i] = *(const short8*)&cA[(wm + i*16 + lr)*32 + t*8];
      #pragma unroll
      for (int j = 0; j < 4; ++j) bfr[j] = *(const short8*)&cB[(wn + j*16 + lr)*32 + t*8];
      #pragma unroll
      for (int i = 0; i < 4; ++i)
        #pragma unroll
        for (int j = 0; j < 4; ++j)
          acc[i][j] = __builtin_amdgcn_mfma_f32_16x16x32_bf16(af[i], bfr[j], acc[i][j], 0, 0, 0);
      __syncthreads();
    }

    short* vx = smem;                    // [128][136] restage buffer
    int b_ = bm >> 11;
    int s0 = bm & 2047;
    // v: transpose restage at PERMUTED row (R24 mapping); copy-out is linear.
    #pragma unroll
    for (int i = 0; i < 4; ++i) {
      int row0 = wm + i*16 + t*4;        // s-base, multiple of 4
      int b4 = (row0 >> 2) & 7;
      int pb = (b4 & 4) | ((b4 & 1) << 1) | ((b4 >> 1) & 1);
      int prow = (row0 & ~31) | (pb << 2);
      #pragma unroll
      for (int j = 0; j < 4; ++j) {
        int cl = wn + j*16 + lr;         // d-col within block
        float bv = bvv[j];
        uint2 pw;
        pw.x = pk_bf16(acc[i][j][0] + bv, acc[i][j][1] + bv);
        pw.y = pk_bf16(acc[i][j][2] + bv, acc[i][j][3] + bv);
        *(uint2*)&vx[cl*136 + prow] = pw;
      }
    }
    __syncthreads();
    int h0 = (bn - 2048) >> 6;
    #pragma unroll
    for (int it = 0; it < 8; ++it) {
      int cc = it * 256 + tid;
      int cl = cc >> 4;
      int ck = cc & 15;
      int h = h0 + (cl >> 6);
      int d = cl & 63;
      *(uint4*)&vw[((size_t)(b_*HH + h)*HD + d)*SS + s0 + ck*8] =
          *(const uint4*)&vx[cl*136 + ck*8];
    }
  } else {
    float4 bq[4];
    #pragma unroll
    for (int j = 0; j < 4; ++j) bq[j] = *(const float4*)&bias[bn + wn + j*16 + t*4];

    // transposed: lane holds 4 consecutive n/d (cols), row = s
    for (int k = 0; k < nk; ++k) {
      if (k + 1 < nk) stage((k + 1) & 1, (k + 1) << 5);
      const short* cA = smem + (k & 1) * 8192;
      const short* cB = smem + (k & 1) * 8192 + 4096;
      short8 af[4], bfr[4];
      #pragma unroll
      for (int i = 0; i < 4; ++i) af[i] = *(const short8*)&cA[(wm + i*16 + lr)*32 + t*8];
      #pragma unroll
      for (int j = 0; j < 4; ++j) bfr[j] = *(const short8*)&cB[(wn + j*16 + lr)*32 + t*8];
      #pragma unroll
      for (int i = 0; i < 4; ++i)
        #pragma unroll
        for (int j = 0; j < 4; ++j)
          acc[i][j] = __builtin_amdgcn_mfma_f32_16x16x32_bf16(bfr[j], af[i], acc[i][j], 0, 0, 0);
      __syncthreads();
    }

    short* vx = smem;                    // [128][136] restage buffer
    int b_ = bm >> 11;
    int s0 = bm & 2047;
    #pragma unroll
    for (int j = 0; j < 4; ++j) {
      int col0 = wn + j*16 + t*4;
      float4 bv4 = bq[j];
      #pragma unroll
      for (int i = 0; i < 4; ++i) {
        int row = wm + i*16 + lr;
        float v0 = acc[i][j][0] + bv4.x;
        float v1 = acc[i][j][1] + bv4.y;
        float v2 = acc[i][j][2] + bv4.z;
        float v3 = acc[i][j][3] + bv4.w;
        if (isQ) { v0 *= QSCALE; v1 *= QSCALE; v2 *= QSCALE; v3 *= QSCALE; }
        uint2 pw;
        pw.x = pk_bf16(v0, v1);
        pw.y = pk_bf16(v2, v3);
        *(uint2*)&vx[row*136 + col0] = pw;
      }
    }
    __syncthreads();
    short* dst = isQ ? qw : kw;
    int h0 = (bn & 1023) >> 6;
    #pragma unroll
    for (int it = 0; it < 8; ++it) {
      int cc = it * 256 + tid;
      int row = cc >> 4;
      int ck = cc & 15;
      int h = h0 + (ck >> 3);
      int d0 = (ck & 7) * 8;
      *(uint4*)&dst[((size_t)(b_*HH + h)*SS + s0 + row)*HD + d0] =
          *(const uint4*)&vx[row*136 + ck*8];
    }
  }
}

// ====== Out-proj GEMM: BM=64 x BN=128 (best-total config), fp32 out, bias prefetched ======
__global__ __launch_bounds__(256) void gemm_out(
    const short* __restrict__ A, const short* __restrict__ Bw,
    const float* __restrict__ bias,
    float* __restrict__ C,
    int M, int N, int K)
{
  __shared__ short smem[12288];
  const int tid = threadIdx.x;
  const int lane = tid & 63;
  const int wv = tid >> 6;
  const int wm = (wv >> 1) * 32;
  const int wn = (wv & 1) * 64;
  const int t = lane >> 4;
  const int lr = lane & 15;
  const int bm = blockIdx.y * 64;
  const int bn = blockIdx.x * 128;

  f32x4 acc[2][4];
  #pragma unroll
  for (int i = 0; i < 2; ++i)
    #pragma unroll
    for (int j = 0; j < 4; ++j) acc[i][j] = (f32x4){0.f, 0.f, 0.f, 0.f};

  float bvo[4];
  #pragma unroll
  for (int j = 0; j < 4; ++j) bvo[j] = bias[bn + wn + j*16 + lr];

  auto stage = [&](int buf, int k0) {
    short* sA = smem + buf * 6144;
    short* sB = smem + buf * 6144 + 2048;
    {
      int c = wv * 64 + lane;
      int row = c >> 2;
      int ch = (c & 3) * 8;
      async_cp16(&A[(size_t)(bm + row) * K + k0 + ch],
                 (char*)sA + (size_t)(wv * 64) * 16);
    }
    #pragma unroll
    for (int it = 0; it < 2; ++it) {
      int c = it * 256 + wv * 64 + lane;
      int row = c >> 2;
      int ch = (c & 3) * 8;
      async_cp16(&Bw[(size_t)(bn + row) * K + k0 + ch],
                 (char*)sB + (size_t)(it * 256 + wv * 64) * 16);
    }
  };

  const int nk = K >> 5;
  stage(0, 0);
  __syncthreads();

  for (int k = 0; k < nk; ++k) {
    if (k + 1 < nk) stage((k + 1) & 1, (k + 1) << 5);
    const short* cA = smem + (k & 1) * 6144;
    const short* cB = smem + (k & 1) * 6144 + 2048;
    short8 af[2], bfr[4];
    #pragma unroll
    for (int i = 0; i < 2; ++i) af[i] = *(const short8*)&cA[(wm + i*16 + lr)*32 + t*8];
    #pragma unroll
    for (int j = 0; j < 4; ++j) bfr[j] = *(const short8*)&cB[(wn + j*16 + lr)*32 + t*8];
    #pragma unroll
    for (int i = 0; i < 2; ++i)
      #pragma unroll
      for (int j = 0; j < 4; ++j)
        acc[i][j] = __builtin_amdgcn_mfma_f32_16x16x32_bf16(af[i], bfr[j], acc[i][j], 0, 0, 0);
    __syncthreads();
  }

  #pragma unroll
  for (int i = 0; i < 2; ++i) {
    int row0 = bm + wm + i*16 + t*4;
    #pragma unroll
    for (int j = 0; j < 4; ++j) {
      int col = bn + wn + j*16 + lr;
      float bv = bvo[j];
      #pragma unroll
      for (int r = 0; r < 4; ++r)
        C[(size_t)(row0 + r) * N + col] = acc[i][j][r] + bv;
    }
  }
}

// ------------- fallback GEMM (fp32 staging convert), for ws < 48 MB -------------
template<int MODE, typename TA>
__global__ __launch_bounds__(256) void gemm_bt(
    const TA* __restrict__ A, const float* __restrict__ Bw,
    const float* __restrict__ bias,
    float* __restrict__ C,
    short* __restrict__ qw, short* __restrict__ kw, short* __restrict__ vw,
    int M, int N, int K)
{
  __shared__ short sA[128*32];
  __shared__ short sB[128*32];
  const int tid = threadIdx.x;
  const int lane = tid & 63;
  const int wv = tid >> 6;
  const int wm = (wv >> 1) * 64;
  const int wn = (wv & 1) * 64;
  const int t = lane >> 4;
  const int lr = lane & 15;
  const int bm = blockIdx.y * 128;
  const int bn = blockIdx.x * 128;

  f32x4 acc[4][4];
  #pragma unroll
  for (int i = 0; i < 4; ++i)
    #pragma unroll
    for (int j = 0; j < 4; ++j) acc[i][j] = (f32x4){0.f, 0.f, 0.f, 0.f};

  for (int k0 = 0; k0 < K; k0 += 32) {
    __syncthreads();
    if constexpr (sizeof(TA) == 4) {
      #pragma unroll
      for (int it = 0; it < 4; ++it) {
        int c = it * 256 + tid;
        int row = c >> 3, ch = (c & 7) * 4;
        float4 va = *(const float4*)&A[(size_t)(bm + row)*K + k0 + ch];
        uint2 pk; pk.x = pk_bf16(va.x, va.y); pk.y = pk_bf16(va.z, va.w);
        *(uint2*)&sA[row*32 + ch] = pk;
      }
    } else {
      #pragma unroll
      for (int it = 0; it < 2; ++it) {
        int c = it * 256 + tid;
        int row = c >> 2, ch = (c & 3) * 8;
        *(uint4*)&sA[row*32 + ch] = *(const uint4*)&A[(size_t)(bm + row)*K + k0 + ch];
      }
    }
    #pragma unroll
    for (int it = 0; it < 4; ++it) {
      int c = it * 256 + tid;
      int row = c >> 3, ch = (c & 7) * 4;
      float4 vb = *(const float4*)&Bw[(size_t)(bn + row)*K + k0 + ch];
      uint2 pk; pk.x = pk_bf16(vb.x, vb.y); pk.y = pk_bf16(vb.z, vb.w);
      *(uint2*)&sB[row*32 + ch] = pk;
    }
    __syncthreads();
    short8 af[4], bfr[4];
    #pragma unroll
    for (int i = 0; i < 4; ++i) af[i] = *(const short8*)&sA[(wm + i*16 + lr)*32 + t*8];
    #pragma unroll
    for (int j = 0; j < 4; ++j) bfr[j] = *(const short8*)&sB[(wn + j*16 + lr)*32 + t*8];
    #pragma unroll
    for (int i = 0; i < 4; ++i)
      #pragma unroll
      for (int j = 0; j < 4; ++j)
        acc[i][j] = __builtin_amdgcn_mfma_f32_16x16x32_bf16(af[i], bfr[j], acc[i][j], 0, 0, 0);
  }

  #pragma unroll
  for (int i = 0; i < 4; ++i) {
    int row0 = bm + wm + i*16 + t*4;
    #pragma unroll
    for (int j = 0; j < 4; ++j) {
      int col = bn + wn + j*16 + lr;
      float bv = bias[col];
      #pragma unroll
      for (int r = 0; r < 4; ++r) {
        float v = acc[i][j][r] + bv;
        int rr = row0 + r;
        if (MODE == 0) {
          C[(size_t)rr * N + col] = v;
        } else {
          int which = col >> 10;
          int e = col & 1023;
          int h = e >> 6, d = e & 63;
          int b_ = rr >> 11, s = rr & 2047;
          if (which == 0)
            qw[((size_t)(b_*HH + h)*SS + s)*HD + d] = f2bf(v * QSCALE);
          else if (which == 1)
            kw[((size_t)(b_*HH + h)*SS + s)*HD + d] = f2bf(v);
          else {
            // R24 kv-permuted V layout (must match gemm_qkv / attn 32x32 PV):
            // stored idx (within 32-group) = 16f + 8h + j holds
            // kv = 16f + 4h + (j&3) + 8*(j>>2)
            int k7 = s & 127;
            int t32 = k7 & 96;
            int kv32 = k7 & 31;
            int f16 = kv32 & 16;
            int rem = kv32 & 15;
            int hh = (rem >> 2) & 1;
            int jj = (rem & 3) | ((rem >> 3) << 2);
            int sp = t32 | f16 | (hh << 3) | jj;
            vw[((size_t)(b_*HH + h)*HD + d)*SS + (s & ~127) + sp] = f2bf(v);
          }
        }
      }
    }
  }
}

// ---------------- causal flash attention: R24 32x32-MFMA kv-split ----------------
// attn was LDS-read-throughput bound (512 ds_read_b128/CU-iter ~= 6144 cy vs
// 6400 cy measured). New decomposition: 8 waves = 4 q-groups (32 q-rows) x
// 2 kv-halves (64 kv of each 128-tile). Per wave-iter: 8 QK + 8 PV
// mfma_32x32x16 + 16 b128 reads -- HALF the LDS traffic at the SAME 16
// waves/CU occupancy (R20's occupancy-halving mistake avoided). NO-RESCALE
// softmax makes the kv-halves independent until one final O/l combine via LDS.
// Layout safety: QK loads A(K)/B(Q) with identical per-lane k-enumeration
// (any consistent enumeration is correct); V's global kv-permutation is
// derived from the HW-verified 32x32 C/D formula so PV's A and B agree
// slot-by-slot regardless of the true hardware k-slot mapping.
// Causal mask (diag tile): wave (g,hf) active for 32-tile tau iff tau <= g;
// exact-diagonal tile tau==g masks reg r where (r&3)+8*(r>>2)+4*hi > (lane&31).
__global__ __launch_bounds__(512, 4) void attn_kernel(
    const short* __restrict__ Q, const short* __restrict__ K,
    const short* __restrict__ Vt, short* __restrict__ O)
{
  __shared__ short sK[2][128*64];   // swizzled: row kv, chunk cc stored at (cc^(kv&7))
  __shared__ short sV[2][64*128];   // swizzled: row d, chunk cc stored at (cc^(d&15))
  const int tid = threadIdx.x;
  const int lane = tid & 63;
  const int w = tid >> 6;           // 0..7
  const int g = w & 3;              // q-group (32 rows)
  const int hf = w >> 2;            // kv-half (64 kv)
  const int lq = lane & 31;
  const int hi = lane >> 5;
  const int blk = blockIdx.x;
  const int qt = (blk < 256) ? (blk >> 5) : (15 - ((blk - 256) >> 5));
  const int bh = blk & 31;
  const int b = bh >> 4, h = bh & 15;
  const short* Qb = Q  + (size_t)bh * SS * HD;
  const short* Kb = K  + (size_t)bh * SS * HD;
  const short* Vb = Vt + (size_t)bh * HD * SS;
  const int qrow0 = qt * 128 + g * 32;

  auto stage = [&](int buf, int kb) {
    #pragma unroll
    for (int it2 = 0; it2 < 2; ++it2) {
      int s = it2 * 512 + tid;
      int krow = s >> 3;
      int kcc = (s & 7) ^ (krow & 7);
      async_cp16(&Kb[(size_t)(kb + krow) * HD + kcc * 8],
                 (char*)sK[buf] + (size_t)(it2 * 512 + w * 64) * 16);
      int d = s >> 4;
      int vcc = (s & 15) ^ (d & 15);
      async_cp16(&Vb[(size_t)d * SS + kb + vcc * 8],
                 (char*)sV[buf] + (size_t)(it2 * 512 + w * 64) * 16);
    }
  };

  // Q fragments: B-operand of 32x32x16, lane holds Q[d-slice][q = qrow0+lq],
  // 8 contiguous d per lane-half -> one b128 per 16-d slice.
  short8 qf[4];
  #pragma unroll
  for (int ds = 0; ds < 4; ++ds)
    qf[ds] = *(const short8*)&Qb[(size_t)(qrow0 + lq) * HD + ds*16 + hi*8];

  f32x16 o0 = (f32x16)(0.0f);       // O^T partial, d-tile 0 (d 0..31)
  f32x16 o1 = (f32x16)(0.0f);       // d-tile 1 (d 32..63)
  float l = 0.f;                    // partial row-sum (this lane-half's kvs)

  const int niter = qt + 1;
  stage(0, 0);
  __syncthreads();
  int cur = 0;

  // ---- full (unmasked) iterations ----
  #pragma unroll 1
  for (int it = 0; it < niter - 1; ++it) {
    stage(cur ^ 1, (it + 1) * 128);
    const short* sKc = sK[cur];
    const short* sVc = sV[cur];

    #pragma unroll
    for (int tp = 0; tp < 2; ++tp) {
      const int tau = 2*hf + tp;    // 32-kv tile within the 128-tile
      f32x16 sc = (f32x16)(0.0f);
      __builtin_amdgcn_s_setprio(1);
      #pragma unroll
      for (int ds = 0; ds < 4; ++ds) {
        int krow = tau*32 + lq;
        int slot = krow*8 + ((ds*2 + hi) ^ (krow & 7));
        short8 kf = *(const short8*)&sKc[slot*8];
        sc = __builtin_amdgcn_mfma_f32_32x32x16_bf16(kf, qf[ds], sc, 0, 0, 0);
      }
      __builtin_amdgcn_s_setprio(0);

      float rs0=0.f, rs1=0.f, rs2=0.f, rs3=0.f;
      #pragma unroll
      for (int r = 0; r < 16; r += 4) {
        sc[r+0] = EXP2F(sc[r+0]); rs0 += sc[r+0];
        sc[r+1] = EXP2F(sc[r+1]); rs1 += sc[r+1];
        sc[r+2] = EXP2F(sc[r+2]); rs2 += sc[r+2];
        sc[r+3] = EXP2F(sc[r+3]); rs3 += sc[r+3];
      }
      l += (rs0 + rs1) + (rs2 + rs3);

      __builtin_amdgcn_s_setprio(1);
      #pragma unroll
      for (int f = 0; f < 2; ++f) {
        union { uint32_t u[4]; short8 s8; } up;
        up.u[0] = pk_bf16(sc[8*f+0], sc[8*f+1]);
        up.u[1] = pk_bf16(sc[8*f+2], sc[8*f+3]);
        up.u[2] = pk_bf16(sc[8*f+4], sc[8*f+5]);
        up.u[3] = pk_bf16(sc[8*f+6], sc[8*f+7]);
        short8 pf = up.s8;
        {
          int d0 = lq;
          int slot = d0*16 + ((tau*4 + f*2 + hi) ^ (d0 & 15));
          short8 vf = *(const short8*)&sVc[slot*8];
          o0 = __builtin_amdgcn_mfma_f32_32x32x16_bf16(vf, pf, o0, 0, 0, 0);
        }
        {
          int d1 = 32 + lq;
          int slot = d1*16 + ((tau*4 + f*2 + hi) ^ (d1 & 15));
          short8 vf = *(const short8*)&sVc[slot*8];
          o1 = __builtin_amdgcn_mfma_f32_32x32x16_bf16(vf, pf, o1, 0, 0, 0);
        }
      }
      __builtin_amdgcn_s_setprio(0);
    }

    __syncthreads();
    cur ^= 1;
  }

  // ---- diagonal (masked) tile ----
  {
    const short* sKc = sK[cur];
    const short* sVc = sV[cur];
    const bool act0 = (2*hf)     <= g;
    const bool act1 = (2*hf + 1) <= g;
    const bool eq0  = (2*hf)     == g;
    const bool eq1  = (2*hf + 1) == g;

    #pragma unroll
    for (int tp = 0; tp < 2; ++tp) {
      const bool act = tp ? act1 : act0;
      const bool eq  = tp ? eq1  : eq0;
      if (!act) continue;           // wave-uniform skip
      const int tau = 2*hf + tp;
      f32x16 sc = (f32x16)(0.0f);
      __builtin_amdgcn_s_setprio(1);
      #pragma unroll
      for (int ds = 0; ds < 4; ++ds) {
        int krow = tau*32 + lq;
        int slot = krow*8 + ((ds*2 + hi) ^ (krow & 7));
        short8 kf = *(const short8*)&sKc[slot*8];
        sc = __builtin_amdgcn_mfma_f32_32x32x16_bf16(kf, qf[ds], sc, 0, 0, 0);
      }
      __builtin_amdgcn_s_setprio(0);

      if (eq) {                     // exact diagonal 32x32 sub-tile
        #pragma unroll
        for (int r = 0; r < 16; ++r) {
          int kvl = (r & 3) + 8*(r >> 2) + 4*hi;
          if (kvl > lq) sc[r] = -1e30f;
        }
      }

      float rs0=0.f, rs1=0.f, rs2=0.f, rs3=0.f;
      #pragma unroll
      for (int r = 0; r < 16; r += 4) {
        sc[r+0] = EXP2F(sc[r+0]); rs0 += sc[r+0];
        sc[r+1] = EXP2F(sc[r+1]); rs1 += sc[r+1];
        sc[r+2] = EXP2F(sc[r+2]); rs2 += sc[r+2];
        sc[r+3] = EXP2F(sc[r+3]); rs3 += sc[r+3];
      }
      l += (rs0 + rs1) + (rs2 + rs3);

      __builtin_amdgcn_s_setprio(1);
      #pragma unroll
      for (int f = 0; f < 2; ++f) {
        union { uint32_t u[4]; short8 s8; } up;
        up.u[0] = pk_bf16(sc[8*f+0], sc[8*f+1]);
        up.u[1] = pk_bf16(sc[8*f+2], sc[8*f+3]);
        up.u[2] = pk_bf16(sc[8*f+4], sc[8*f+5]);
        up.u[3] = pk_bf16(sc[8*f+6], sc[8*f+7]);
        short8 pf = up.s8;
        {
          int d0 = lq;
          int slot = d0*16 + ((tau*4 + f*2 + hi) ^ (d0 & 15));
          short8 vf = *(const short8*)&sVc[slot*8];
          o0 = __builtin_amdgcn_mfma_f32_32x32x16_bf16(vf, pf, o0, 0, 0, 0);
        }
        {
          int d1 = 32 + lq;
          int slot = d1*16 + ((tau*4 + f*2 + hi) ^ (d1 & 15));
          short8 vf = *(const short8*)&sVc[slot*8];
          o1 = __builtin_amdgcn_mfma_f32_32x32x16_bf16(vf, pf, o1, 0, 0, 0);
        }
      }
      __builtin_amdgcn_s_setprio(0);
    }
  }

  // ---- combine kv-halves (one-time LDS exchange) + writeout ----
  l += __shfl_xor(l, 32);           // lane halves hold complementary kvs

  float* fx = (float*)&sK[0][0];    // 8 regions x 1024 f32 = 32 KB (all of sK)
  float* fl = (float*)&sV[0][0];    // l partials: 8 x 32 f32

  __syncthreads();                  // all K/V LDS reads complete
  // give away the d-tile we DON'T write out: hf=0 gives o1 (dt=1), hf=1 gives o0
  {
    float* reg = fx + (size_t)(g*2 + (1 - hf)) * 1024;
    if (hf == 0) {
      #pragma unroll
      for (int i = 0; i < 16; ++i) reg[i*64 + lane] = o1[i];
    } else {
      #pragma unroll
      for (int i = 0; i < 16; ++i) reg[i*64 + lane] = o0[i];
    }
    if (lane < 32) fl[w*32 + lq] = l;
  }
  __syncthreads();
  {
    float lp = fl[(g + 4*(1 - hf))*32 + lq];   // partner wave's l partial
    float linv = 1.0f / (l + lp);
    float* reg = fx + (size_t)(g*2 + hf) * 1024;
    float ov[16];
    if (hf == 0) {
      #pragma unroll
      for (int i = 0; i < 16; ++i) ov[i] = (o0[i] + reg[i*64 + lane]) * linv;
    } else {
      #pragma unroll
      for (int i = 0; i < 16; ++i) ov[i] = (o1[i] + reg[i*64 + lane]) * linv;
    }
    // writeout d-tile hf: q = qrow0 + lq; d = hf*32 + 8*grp + 4*hi + (r&3)
    size_t rowoff = ((size_t)(b * SS + qrow0 + lq)) * EE + h * HD + hf*32 + hi*4;
    #pragma unroll
    for (int grp = 0; grp < 4; ++grp) {
      uint2 pw;
      pw.x = pk_bf16(ov[grp*4+0], ov[grp*4+1]);
      pw.y = pk_bf16(ov[grp*4+2], ov[grp*4+3]);
      *(uint2*)&O[rowoff + grp*8] = pw;
    }
  }
}

extern "C" void kernel_launch(void* const* d_in, const int* in_sizes, int n_in,
                              void* d_out, int out_size, void* d_ws, size_t ws_size,
                              hipStream_t stream) {
  const float* X     = (const float*)d_in[0];
  const float* W_in  = (const float*)d_in[1];
  const float* b_in  = (const float*)d_in[2];
  const float* W_out = (const float*)d_in[3];
  const float* b_out = (const float*)d_in[4];
  float* out = (float*)d_out;

  char* ws = (char*)d_ws;
  const size_t MB = 1024 * 1024;
  const int M = 2 * SS;  // 4096

  if (ws_size >= 48 * MB) {
    short* Xb   = (short*)(ws);
    short* Wb1  = (short*)(ws + 8  * MB);
    short* Wb2  = (short*)(ws + 14 * MB);
    short* q_ws = (short*)(ws + 16 * MB);
    short* k_ws = (short*)(ws + 24 * MB);
    short* v_ws = (short*)(ws + 32 * MB);
    short* attn = (short*)(ws + 40 * MB);

    cvt_all<<<2048, 256, 0, stream>>>(X, W_in, W_out, Xb, Wb1, Wb2);
    gemm_qkv<<<dim3(24, 32), 256, 0, stream>>>(
        Xb, Wb1, b_in, q_ws, k_ws, v_ws, M, 3 * EE, EE);
    attn_kernel<<<dim3(512), 512, 0, stream>>>(q_ws, k_ws, v_ws, attn);
    gemm_out<<<dim3(8, 64), 256, 0, stream>>>(
        attn, Wb2, b_out, out, M, EE, EE);
  } else {
    short* q_ws = (short*)(ws);
    short* k_ws = (short*)(ws + 8  * MB);
    short* v_ws = (short*)(ws + 16 * MB);
    short* attn = (short*)(ws + 24 * MB);

    gemm_bt<1, float><<<dim3(24, 32), 256, 0, stream>>>(
        X, W_in, b_in, nullptr, q_ws, k_ws, v_ws, M, 3 * EE, EE);
    attn_kernel<<<dim3(512), 512, 0, stream>>>(q_ws, k_ws, v_ws, attn);
    gemm_bt<0, short><<<dim3(8, 32), 256, 0, stream>>>(
        attn, W_out, b_out, out, nullptr, nullptr, nullptr, M, EE, EE);
  }
}

// Round 12
// 168.519 us; speedup vs baseline: 1.1375x; 1.1375x over previous
//
#include <hip/hip_runtime.h>
#include <hip/hip_bf16.h>
#include <stdint.h>

// Problem constants: B=2, S=2048, E=1024, H=16, hd=64.
#define SS 2048
#define EE 1024
#define HH 16
#define HD 64

// 0.125 (1/sqrt(hd)) * log2(e): scores come out of QK^T already in exp2-domain.
#define QSCALE 0.1803368801111137f

typedef __attribute__((ext_vector_type(8))) short short8;
typedef __attribute__((ext_vector_type(4))) float f32x4;
typedef __attribute__((ext_vector_type(16))) float f32x16;

__device__ __forceinline__ short f2bf(float f) {
  union { float f; uint32_t u; } x; x.f = f;
  uint32_t r = x.u + 0x7fffu + ((x.u >> 16) & 1u);
  return (short)(r >> 16);
}

__device__ __forceinline__ uint32_t pk_bf16(float a, float b) {
#if __has_builtin(__builtin_amdgcn_cvt_pk_bf16_f32)
  typedef __attribute__((ext_vector_type(2))) __bf16 bf16x2_t;
  union { bf16x2_t v; uint32_t u; } x;
  x.v = __builtin_amdgcn_cvt_pk_bf16_f32(a, b);
  return x.u;
#else
  return (uint32_t)(uint16_t)f2bf(a) | ((uint32_t)(uint16_t)f2bf(b) << 16);
#endif
}

#if __has_builtin(__builtin_amdgcn_exp2f)
#define EXP2F __builtin_amdgcn_exp2f
#else
#define EXP2F exp2f
#endif

__device__ __forceinline__ void async_cp16(const void* g, void* l) {
  __builtin_amdgcn_global_load_lds((const __attribute__((address_space(1))) void*)g,
                                   (__attribute__((address_space(3))) void*)l, 16, 0, 0);
}

// ---------------- fp32 -> bf16 pre-convert (X, W_in, W_out) ----------------
// Grid-stride at 2048 blocks (G11). Measured ~6 TB/s -> at HBM roofline.
#define N4_X  1048576
#define N4_W1 786432
#define N4_W2 262144
#define N4_ALL (N4_X + N4_W1 + N4_W2)
__global__ __launch_bounds__(256) void cvt_all(
    const float* __restrict__ x, const float* __restrict__ w1,
    const float* __restrict__ w2,
    short* __restrict__ xb, short* __restrict__ w1b, short* __restrict__ w2b)
{
  for (int i = blockIdx.x * 256 + threadIdx.x; i < N4_ALL; i += 2048 * 256) {
    const float* src; short* dst; int off;
    if (i < N4_X)            { src = x;  dst = xb;  off = i; }
    else if (i < N4_X+N4_W1) { src = w1; dst = w1b; off = i - N4_X; }
    else                     { src = w2; dst = w2b; off = i - N4_X - N4_W1; }
    float4 v = *(const float4*)&src[(size_t)off * 4];
    uint2 pk;
    pk.x = pk_bf16(v.x, v.y);
    pk.y = pk_bf16(v.z, v.w);
    *(uint2*)&dst[(size_t)off * 4] = pk;
  }
}

// ====== QKV GEMM: BM=128 x BN=128, BK=32, dbuf async global->LDS (R18 loop) ======
// Orientation branch hoisted OUT of the K-loop (R2/R3 lesson). Bias loads
// hoisted above the K-loop (R23). NO manual vmcnt/sched_barrier (R19 lesson).
// V layout NOTE (R24, matches attn 32x32 kv-split): within each 32-aligned
// s-subgroup, stored position 16f + 8h + j holds kv = 16f + 4h + (j&3) + 8*(j>>2)
// (f,h in {0,1}, j in [0,8)). At 4-block granularity this is a bit0<->bit1 swap
// of the 4-block index within each 32-group; order inside 4-blocks preserved.
__global__ __launch_bounds__(256) void gemm_qkv(
    const short* __restrict__ A, const short* __restrict__ Bw,
    const float* __restrict__ bias,
    short* __restrict__ qw, short* __restrict__ kw, short* __restrict__ vw,
    int M, int N, int K)
{
  __shared__ short smem[17408];
  const int tid = threadIdx.x;
  const int lane = tid & 63;
  const int wv = tid >> 6;
  const int wm = (wv >> 1) * 64;
  const int wn = (wv & 1) * 64;
  const int t = lane >> 4;
  const int lr = lane & 15;
  const int bm = blockIdx.y * 128;
  const int bn = blockIdx.x * 128;

  f32x4 acc[4][4];
  #pragma unroll
  for (int i = 0; i < 4; ++i)
    #pragma unroll
    for (int j = 0; j < 4; ++j) acc[i][j] = (f32x4){0.f, 0.f, 0.f, 0.f};

  auto stage = [&](int buf, int k0) {
    short* sA = smem + buf * 8192;
    short* sB = smem + buf * 8192 + 4096;
    #pragma unroll
    for (int it = 0; it < 2; ++it) {
      int c = it * 256 + wv * 64 + lane;
      int row = c >> 2;
      int ch = (c & 3) * 8;
      async_cp16(&A[(size_t)(bm + row) * K + k0 + ch],
                 (char*)sA + (size_t)(it * 256 + wv * 64) * 16);
      async_cp16(&Bw[(size_t)(bn + row) * K + k0 + ch],
                 (char*)sB + (size_t)(it * 256 + wv * 64) * 16);
    }
  };

  const bool isV = (bn >= 2048);
  const bool isQ = (bn < 1024);
  const int nk = K >> 5;
  stage(0, 0);
  __syncthreads();

  if (isV) {
    float bvv[4];
    #pragma unroll
    for (int j = 0; j < 4; ++j) bvv[j] = bias[bn + wn + j*16 + lr];

    // original orientation: lane holds 4 consecutive s (rows), col = d
    for (int k = 0; k < nk; ++k) {
      if (k + 1 < nk) stage((k + 1) & 1, (k + 1) << 5);
      const short* cA = smem + (k & 1) * 8192;
      const short* cB = smem + (k & 1) * 8192 + 4096;
      short8 af[4], bfr[4];
      #pragma unroll
      for (int i = 0; i < 4; ++i) af[i] = *(const short8*)&cA[(wm + i*16 + lr)*32 + t*8];
      #pragma unroll
      for (int j = 0; j < 4; ++j) bfr[j] = *(const short8*)&cB[(wn + j*16 + lr)*32 + t*8];
      #pragma unroll
      for (int i = 0; i < 4; ++i)
        #pragma unroll
        for (int j = 0; j < 4; ++j)
          acc[i][j] = __builtin_amdgcn_mfma_f32_16x16x32_bf16(af[i], bfr[j], acc[i][j], 0, 0, 0);
      __syncthreads();
    }

    short* vx = smem;                    // [128][136] restage buffer
    int b_ = bm >> 11;
    int s0 = bm & 2047;
    // v: transpose restage at PERMUTED row (R24 mapping); copy-out is linear.
    #pragma unroll
    for (int i = 0; i < 4; ++i) {
      int row0 = wm + i*16 + t*4;        // s-base, multiple of 4
      int b4 = (row0 >> 2) & 7;
      int pb = (b4 & 4) | ((b4 & 1) << 1) | ((b4 >> 1) & 1);
      int prow = (row0 & ~31) | (pb << 2);
      #pragma unroll
      for (int j = 0; j < 4; ++j) {
        int cl = wn + j*16 + lr;         // d-col within block
        float bv = bvv[j];
        uint2 pw;
        pw.x = pk_bf16(acc[i][j][0] + bv, acc[i][j][1] + bv);
        pw.y = pk_bf16(acc[i][j][2] + bv, acc[i][j][3] + bv);
        *(uint2*)&vx[cl*136 + prow] = pw;
      }
    }
    __syncthreads();
    int h0 = (bn - 2048) >> 6;
    #pragma unroll
    for (int it = 0; it < 8; ++it) {
      int cc = it * 256 + tid;
      int cl = cc >> 4;
      int ck = cc & 15;
      int h = h0 + (cl >> 6);
      int d = cl & 63;
      *(uint4*)&vw[((size_t)(b_*HH + h)*HD + d)*SS + s0 + ck*8] =
          *(const uint4*)&vx[cl*136 + ck*8];
    }
  } else {
    float4 bq[4];
    #pragma unroll
    for (int j = 0; j < 4; ++j) bq[j] = *(const float4*)&bias[bn + wn + j*16 + t*4];

    // transposed: lane holds 4 consecutive n/d (cols), row = s
    for (int k = 0; k < nk; ++k) {
      if (k + 1 < nk) stage((k + 1) & 1, (k + 1) << 5);
      const short* cA = smem + (k & 1) * 8192;
      const short* cB = smem + (k & 1) * 8192 + 4096;
      short8 af[4], bfr[4];
      #pragma unroll
      for (int i = 0; i < 4; ++i) af[i] = *(const short8*)&cA[(wm + i*16 + lr)*32 + t*8];
      #pragma unroll
      for (int j = 0; j < 4; ++j) bfr[j] = *(const short8*)&cB[(wn + j*16 + lr)*32 + t*8];
      #pragma unroll
      for (int i = 0; i < 4; ++i)
        #pragma unroll
        for (int j = 0; j < 4; ++j)
          acc[i][j] = __builtin_amdgcn_mfma_f32_16x16x32_bf16(bfr[j], af[i], acc[i][j], 0, 0, 0);
      __syncthreads();
    }

    short* vx = smem;                    // [128][136] restage buffer
    int b_ = bm >> 11;
    int s0 = bm & 2047;
    #pragma unroll
    for (int j = 0; j < 4; ++j) {
      int col0 = wn + j*16 + t*4;
      float4 bv4 = bq[j];
      #pragma unroll
      for (int i = 0; i < 4; ++i) {
        int row = wm + i*16 + lr;
        float v0 = acc[i][j][0] + bv4.x;
        float v1 = acc[i][j][1] + bv4.y;
        float v2 = acc[i][j][2] + bv4.z;
        float v3 = acc[i][j][3] + bv4.w;
        if (isQ) { v0 *= QSCALE; v1 *= QSCALE; v2 *= QSCALE; v3 *= QSCALE; }
        uint2 pw;
        pw.x = pk_bf16(v0, v1);
        pw.y = pk_bf16(v2, v3);
        *(uint2*)&vx[row*136 + col0] = pw;
      }
    }
    __syncthreads();
    short* dst = isQ ? qw : kw;
    int h0 = (bn & 1023) >> 6;
    #pragma unroll
    for (int it = 0; it < 8; ++it) {
      int cc = it * 256 + tid;
      int row = cc >> 4;
      int ck = cc & 15;
      int h = h0 + (ck >> 3);
      int d0 = (ck & 7) * 8;
      *(uint4*)&dst[((size_t)(b_*HH + h)*SS + s0 + row)*HD + d0] =
          *(const uint4*)&vx[row*136 + ck*8];
    }
  }
}

// ====== Out-proj GEMM: BM=64 x BN=128 (best-total config), fp32 out, bias prefetched ======
__global__ __launch_bounds__(256) void gemm_out(
    const short* __restrict__ A, const short* __restrict__ Bw,
    const float* __restrict__ bias,
    float* __restrict__ C,
    int M, int N, int K)
{
  __shared__ short smem[12288];
  const int tid = threadIdx.x;
  const int lane = tid & 63;
  const int wv = tid >> 6;
  const int wm = (wv >> 1) * 32;
  const int wn = (wv & 1) * 64;
  const int t = lane >> 4;
  const int lr = lane & 15;
  const int bm = blockIdx.y * 64;
  const int bn = blockIdx.x * 128;

  f32x4 acc[2][4];
  #pragma unroll
  for (int i = 0; i < 2; ++i)
    #pragma unroll
    for (int j = 0; j < 4; ++j) acc[i][j] = (f32x4){0.f, 0.f, 0.f, 0.f};

  float bvo[4];
  #pragma unroll
  for (int j = 0; j < 4; ++j) bvo[j] = bias[bn + wn + j*16 + lr];

  auto stage = [&](int buf, int k0) {
    short* sA = smem + buf * 6144;
    short* sB = smem + buf * 6144 + 2048;
    {
      int c = wv * 64 + lane;
      int row = c >> 2;
      int ch = (c & 3) * 8;
      async_cp16(&A[(size_t)(bm + row) * K + k0 + ch],
                 (char*)sA + (size_t)(wv * 64) * 16);
    }
    #pragma unroll
    for (int it = 0; it < 2; ++it) {
      int c = it * 256 + wv * 64 + lane;
      int row = c >> 2;
      int ch = (c & 3) * 8;
      async_cp16(&Bw[(size_t)(bn + row) * K + k0 + ch],
                 (char*)sB + (size_t)(it * 256 + wv * 64) * 16);
    }
  };

  const int nk = K >> 5;
  stage(0, 0);
  __syncthreads();

  for (int k = 0; k < nk; ++k) {
    if (k + 1 < nk) stage((k + 1) & 1, (k + 1) << 5);
    const short* cA = smem + (k & 1) * 6144;
    const short* cB = smem + (k & 1) * 6144 + 2048;
    short8 af[2], bfr[4];
    #pragma unroll
    for (int i = 0; i < 2; ++i) af[i] = *(const short8*)&cA[(wm + i*16 + lr)*32 + t*8];
    #pragma unroll
    for (int j = 0; j < 4; ++j) bfr[j] = *(const short8*)&cB[(wn + j*16 + lr)*32 + t*8];
    #pragma unroll
    for (int i = 0; i < 2; ++i)
      #pragma unroll
      for (int j = 0; j < 4; ++j)
        acc[i][j] = __builtin_amdgcn_mfma_f32_16x16x32_bf16(af[i], bfr[j], acc[i][j], 0, 0, 0);
    __syncthreads();
  }

  #pragma unroll
  for (int i = 0; i < 2; ++i) {
    int row0 = bm + wm + i*16 + t*4;
    #pragma unroll
    for (int j = 0; j < 4; ++j) {
      int col = bn + wn + j*16 + lr;
      float bv = bvo[j];
      #pragma unroll
      for (int r = 0; r < 4; ++r)
        C[(size_t)(row0 + r) * N + col] = acc[i][j][r] + bv;
    }
  }
}

// ------------- fallback GEMM (fp32 staging convert), for ws < 48 MB -------------
template<int MODE, typename TA>
__global__ __launch_bounds__(256) void gemm_bt(
    const TA* __restrict__ A, const float* __restrict__ Bw,
    const float* __restrict__ bias,
    float* __restrict__ C,
    short* __restrict__ qw, short* __restrict__ kw, short* __restrict__ vw,
    int M, int N, int K)
{
  __shared__ short sA[128*32];
  __shared__ short sB[128*32];
  const int tid = threadIdx.x;
  const int lane = tid & 63;
  const int wv = tid >> 6;
  const int wm = (wv >> 1) * 64;
  const int wn = (wv & 1) * 64;
  const int t = lane >> 4;
  const int lr = lane & 15;
  const int bm = blockIdx.y * 128;
  const int bn = blockIdx.x * 128;

  f32x4 acc[4][4];
  #pragma unroll
  for (int i = 0; i < 4; ++i)
    #pragma unroll
    for (int j = 0; j < 4; ++j) acc[i][j] = (f32x4){0.f, 0.f, 0.f, 0.f};

  for (int k0 = 0; k0 < K; k0 += 32) {
    __syncthreads();
    if constexpr (sizeof(TA) == 4) {
      #pragma unroll
      for (int it = 0; it < 4; ++it) {
        int c = it * 256 + tid;
        int row = c >> 3, ch = (c & 7) * 4;
        float4 va = *(const float4*)&A[(size_t)(bm + row)*K + k0 + ch];
        uint2 pk; pk.x = pk_bf16(va.x, va.y); pk.y = pk_bf16(va.z, va.w);
        *(uint2*)&sA[row*32 + ch] = pk;
      }
    } else {
      #pragma unroll
      for (int it = 0; it < 2; ++it) {
        int c = it * 256 + tid;
        int row = c >> 2, ch = (c & 3) * 8;
        *(uint4*)&sA[row*32 + ch] = *(const uint4*)&A[(size_t)(bm + row)*K + k0 + ch];
      }
    }
    #pragma unroll
    for (int it = 0; it < 4; ++it) {
      int c = it * 256 + tid;
      int row = c >> 3, ch = (c & 7) * 4;
      float4 vb = *(const float4*)&Bw[(size_t)(bn + row)*K + k0 + ch];
      uint2 pk; pk.x = pk_bf16(vb.x, vb.y); pk.y = pk_bf16(vb.z, vb.w);
      *(uint2*)&sB[row*32 + ch] = pk;
    }
    __syncthreads();
    short8 af[4], bfr[4];
    #pragma unroll
    for (int i = 0; i < 4; ++i) af[i] = *(const short8*)&sA[(wm + i*16 + lr)*32 + t*8];
    #pragma unroll
    for (int j = 0; j < 4; ++j) bfr[j] = *(const short8*)&sB[(wn + j*16 + lr)*32 + t*8];
    #pragma unroll
    for (int i = 0; i < 4; ++i)
      #pragma unroll
      for (int j = 0; j < 4; ++j)
        acc[i][j] = __builtin_amdgcn_mfma_f32_16x16x32_bf16(af[i], bfr[j], acc[i][j], 0, 0, 0);
  }

  #pragma unroll
  for (int i = 0; i < 4; ++i) {
    int row0 = bm + wm + i*16 + t*4;
    #pragma unroll
    for (int j = 0; j < 4; ++j) {
      int col = bn + wn + j*16 + lr;
      float bv = bias[col];
      #pragma unroll
      for (int r = 0; r < 4; ++r) {
        float v = acc[i][j][r] + bv;
        int rr = row0 + r;
        if (MODE == 0) {
          C[(size_t)rr * N + col] = v;
        } else {
          int which = col >> 10;
          int e = col & 1023;
          int h = e >> 6, d = e & 63;
          int b_ = rr >> 11, s = rr & 2047;
          if (which == 0)
            qw[((size_t)(b_*HH + h)*SS + s)*HD + d] = f2bf(v * QSCALE);
          else if (which == 1)
            kw[((size_t)(b_*HH + h)*SS + s)*HD + d] = f2bf(v);
          else {
            // R24 kv-permuted V layout (must match gemm_qkv / attn 32x32 PV):
            // stored idx (within 32-group) = 16f + 8h + j holds
            // kv = 16f + 4h + (j&3) + 8*(j>>2)
            int k7 = s & 127;
            int t32 = k7 & 96;
            int kv32 = k7 & 31;
            int f16 = kv32 & 16;
            int rem = kv32 & 15;
            int hh = (rem >> 2) & 1;
            int jj = (rem & 3) | ((rem >> 3) << 2);
            int sp = t32 | f16 | (hh << 3) | jj;
            vw[((size_t)(b_*HH + h)*HD + d)*SS + (s & ~127) + sp] = f2bf(v);
          }
        }
      }
    }
  }
}

// ---------------- causal flash attention: R24 32x32-MFMA kv-split ----------------
// attn was LDS-read-throughput bound (512 ds_read_b128/CU-iter ~= 6144 cy vs
// 6400 cy measured). Decomposition: 8 waves = 4 q-groups (32 q-rows) x
// 2 kv-halves (64 kv of each 128-tile). Per wave-iter: 8 QK + 8 PV
// mfma_32x32x16 + 16 b128 reads -- HALF the LDS traffic at the SAME 16
// waves/CU occupancy. NO-RESCALE softmax makes the kv-halves independent
// until one final O/l combine via LDS.
// R25 FIX: launch_bounds was (512,4) -- this hipcc treats arg2 CUDA-style as
// min BLOCKS/CU (measured: VGPR capped at 64 = 2048/32waves -> accumulator
// spills, +50GB scratch traffic). (512,2) => 2 blocks/CU => cap 128 VGPR,
// which is both the LDS-dictated occupancy and enough regs (no spill).
// Layout safety: QK loads A(K)/B(Q) with identical per-lane k-enumeration;
// V's global kv-permutation is derived from the HW-verified 32x32 C/D formula
// so PV's A and B agree slot-by-slot regardless of the true k-slot mapping.
__global__ __launch_bounds__(512, 2) void attn_kernel(
    const short* __restrict__ Q, const short* __restrict__ K,
    const short* __restrict__ Vt, short* __restrict__ O)
{
  __shared__ short sK[2][128*64];   // swizzled: row kv, chunk cc stored at (cc^(kv&7))
  __shared__ short sV[2][64*128];   // swizzled: row d, chunk cc stored at (cc^(d&15))
  const int tid = threadIdx.x;
  const int lane = tid & 63;
  const int w = tid >> 6;           // 0..7
  const int g = w & 3;              // q-group (32 rows)
  const int hf = w >> 2;            // kv-half (64 kv)
  const int lq = lane & 31;
  const int hi = lane >> 5;
  const int blk = blockIdx.x;
  const int qt = (blk < 256) ? (blk >> 5) : (15 - ((blk - 256) >> 5));
  const int bh = blk & 31;
  const int b = bh >> 4, h = bh & 15;
  const short* Qb = Q  + (size_t)bh * SS * HD;
  const short* Kb = K  + (size_t)bh * SS * HD;
  const short* Vb = Vt + (size_t)bh * HD * SS;
  const int qrow0 = qt * 128 + g * 32;

  auto stage = [&](int buf, int kb) {
    #pragma unroll
    for (int it2 = 0; it2 < 2; ++it2) {
      int s = it2 * 512 + tid;
      int krow = s >> 3;
      int kcc = (s & 7) ^ (krow & 7);
      async_cp16(&Kb[(size_t)(kb + krow) * HD + kcc * 8],
                 (char*)sK[buf] + (size_t)(it2 * 512 + w * 64) * 16);
      int d = s >> 4;
      int vcc = (s & 15) ^ (d & 15);
      async_cp16(&Vb[(size_t)d * SS + kb + vcc * 8],
                 (char*)sV[buf] + (size_t)(it2 * 512 + w * 64) * 16);
    }
  };

  // Q fragments: B-operand of 32x32x16, lane holds Q[d-slice][q = qrow0+lq],
  // 8 contiguous d per lane-half -> one b128 per 16-d slice.
  short8 qf[4];
  #pragma unroll
  for (int ds = 0; ds < 4; ++ds)
    qf[ds] = *(const short8*)&Qb[(size_t)(qrow0 + lq) * HD + ds*16 + hi*8];

  f32x16 o0 = (f32x16)(0.0f);       // O^T partial, d-tile 0 (d 0..31)
  f32x16 o1 = (f32x16)(0.0f);       // d-tile 1 (d 32..63)
  float l = 0.f;                    // partial row-sum (this lane-half's kvs)

  const int niter = qt + 1;
  stage(0, 0);
  __syncthreads();
  int cur = 0;

  // ---- full (unmasked) iterations ----
  #pragma unroll 1
  for (int it = 0; it < niter - 1; ++it) {
    stage(cur ^ 1, (it + 1) * 128);
    const short* sKc = sK[cur];
    const short* sVc = sV[cur];

    #pragma unroll
    for (int tp = 0; tp < 2; ++tp) {
      const int tau = 2*hf + tp;    // 32-kv tile within the 128-tile
      f32x16 sc = (f32x16)(0.0f);
      __builtin_amdgcn_s_setprio(1);
      #pragma unroll
      for (int ds = 0; ds < 4; ++ds) {
        int krow = tau*32 + lq;
        int slot = krow*8 + ((ds*2 + hi) ^ (krow & 7));
        short8 kf = *(const short8*)&sKc[slot*8];
        sc = __builtin_amdgcn_mfma_f32_32x32x16_bf16(kf, qf[ds], sc, 0, 0, 0);
      }
      __builtin_amdgcn_s_setprio(0);

      float rs0=0.f, rs1=0.f, rs2=0.f, rs3=0.f;
      #pragma unroll
      for (int r = 0; r < 16; r += 4) {
        sc[r+0] = EXP2F(sc[r+0]); rs0 += sc[r+0];
        sc[r+1] = EXP2F(sc[r+1]); rs1 += sc[r+1];
        sc[r+2] = EXP2F(sc[r+2]); rs2 += sc[r+2];
        sc[r+3] = EXP2F(sc[r+3]); rs3 += sc[r+3];
      }
      l += (rs0 + rs1) + (rs2 + rs3);

      __builtin_amdgcn_s_setprio(1);
      #pragma unroll
      for (int f = 0; f < 2; ++f) {
        union { uint32_t u[4]; short8 s8; } up;
        up.u[0] = pk_bf16(sc[8*f+0], sc[8*f+1]);
        up.u[1] = pk_bf16(sc[8*f+2], sc[8*f+3]);
        up.u[2] = pk_bf16(sc[8*f+4], sc[8*f+5]);
        up.u[3] = pk_bf16(sc[8*f+6], sc[8*f+7]);
        short8 pf = up.s8;
        {
          int d0 = lq;
          int slot = d0*16 + ((tau*4 + f*2 + hi) ^ (d0 & 15));
          short8 vf = *(const short8*)&sVc[slot*8];
          o0 = __builtin_amdgcn_mfma_f32_32x32x16_bf16(vf, pf, o0, 0, 0, 0);
        }
        {
          int d1 = 32 + lq;
          int slot = d1*16 + ((tau*4 + f*2 + hi) ^ (d1 & 15));
          short8 vf = *(const short8*)&sVc[slot*8];
          o1 = __builtin_amdgcn_mfma_f32_32x32x16_bf16(vf, pf, o1, 0, 0, 0);
        }
      }
      __builtin_amdgcn_s_setprio(0);
    }

    __syncthreads();
    cur ^= 1;
  }

  // ---- diagonal (masked) tile ----
  {
    const short* sKc = sK[cur];
    const short* sVc = sV[cur];
    const bool act0 = (2*hf)     <= g;
    const bool act1 = (2*hf + 1) <= g;
    const bool eq0  = (2*hf)     == g;
    const bool eq1  = (2*hf + 1) == g;

    #pragma unroll
    for (int tp = 0; tp < 2; ++tp) {
      const bool act = tp ? act1 : act0;
      const bool eq  = tp ? eq1  : eq0;
      if (!act) continue;           // wave-uniform skip
      const int tau = 2*hf + tp;
      f32x16 sc = (f32x16)(0.0f);
      __builtin_amdgcn_s_setprio(1);
      #pragma unroll
      for (int ds = 0; ds < 4; ++ds) {
        int krow = tau*32 + lq;
        int slot = krow*8 + ((ds*2 + hi) ^ (krow & 7));
        short8 kf = *(const short8*)&sKc[slot*8];
        sc = __builtin_amdgcn_mfma_f32_32x32x16_bf16(kf, qf[ds], sc, 0, 0, 0);
      }
      __builtin_amdgcn_s_setprio(0);

      if (eq) {                     // exact diagonal 32x32 sub-tile
        #pragma unroll
        for (int r = 0; r < 16; ++r) {
          int kvl = (r & 3) + 8*(r >> 2) + 4*hi;
          if (kvl > lq) sc[r] = -1e30f;
        }
      }

      float rs0=0.f, rs1=0.f, rs2=0.f, rs3=0.f;
      #pragma unroll
      for (int r = 0; r < 16; r += 4) {
        sc[r+0] = EXP2F(sc[r+0]); rs0 += sc[r+0];
        sc[r+1] = EXP2F(sc[r+1]); rs1 += sc[r+1];
        sc[r+2] = EXP2F(sc[r+2]); rs2 += sc[r+2];
        sc[r+3] = EXP2F(sc[r+3]); rs3 += sc[r+3];
      }
      l += (rs0 + rs1) + (rs2 + rs3);

      __builtin_amdgcn_s_setprio(1);
      #pragma unroll
      for (int f = 0; f < 2; ++f) {
        union { uint32_t u[4]; short8 s8; } up;
        up.u[0] = pk_bf16(sc[8*f+0], sc[8*f+1]);
        up.u[1] = pk_bf16(sc[8*f+2], sc[8*f+3]);
        up.u[2] = pk_bf16(sc[8*f+4], sc[8*f+5]);
        up.u[3] = pk_bf16(sc[8*f+6], sc[8*f+7]);
        short8 pf = up.s8;
        {
          int d0 = lq;
          int slot = d0*16 + ((tau*4 + f*2 + hi) ^ (d0 & 15));
          short8 vf = *(const short8*)&sVc[slot*8];
          o0 = __builtin_amdgcn_mfma_f32_32x32x16_bf16(vf, pf, o0, 0, 0, 0);
        }
        {
          int d1 = 32 + lq;
          int slot = d1*16 + ((tau*4 + f*2 + hi) ^ (d1 & 15));
          short8 vf = *(const short8*)&sVc[slot*8];
          o1 = __builtin_amdgcn_mfma_f32_32x32x16_bf16(vf, pf, o1, 0, 0, 0);
        }
      }
      __builtin_amdgcn_s_setprio(0);
    }
  }

  // ---- combine kv-halves (one-time LDS exchange) + writeout ----
  l += __shfl_xor(l, 32);           // lane halves hold complementary kvs

  float* fx = (float*)&sK[0][0];    // 8 regions x 1024 f32 = 32 KB (all of sK)
  float* fl = (float*)&sV[0][0];    // l partials: 8 x 32 f32

  __syncthreads();                  // all K/V LDS reads complete
  // give away the d-tile we DON'T write out: hf=0 gives o1 (dt=1), hf=1 gives o0
  {
    float* reg = fx + (size_t)(g*2 + (1 - hf)) * 1024;
    if (hf == 0) {
      #pragma unroll
      for (int i = 0; i < 16; ++i) reg[i*64 + lane] = o1[i];
    } else {
      #pragma unroll
      for (int i = 0; i < 16; ++i) reg[i*64 + lane] = o0[i];
    }
    if (lane < 32) fl[w*32 + lq] = l;
  }
  __syncthreads();
  {
    float lp = fl[(g + 4*(1 - hf))*32 + lq];   // partner wave's l partial
    float linv = 1.0f / (l + lp);
    float* reg = fx + (size_t)(g*2 + hf) * 1024;
    float ov[16];
    if (hf == 0) {
      #pragma unroll
      for (int i = 0; i < 16; ++i) ov[i] = (o0[i] + reg[i*64 + lane]) * linv;
    } else {
      #pragma unroll
      for (int i = 0; i < 16; ++i) ov[i] = (o1[i] + reg[i*64 + lane]) * linv;
    }
    // writeout d-tile hf: q = qrow0 + lq; d = hf*32 + 8*grp + 4*hi + (r&3)
    size_t rowoff = ((size_t)(b * SS + qrow0 + lq)) * EE + h * HD + hf*32 + hi*4;
    #pragma unroll
    for (int grp = 0; grp < 4; ++grp) {
      uint2 pw;
      pw.x = pk_bf16(ov[grp*4+0], ov[grp*4+1]);
      pw.y = pk_bf16(ov[grp*4+2], ov[grp*4+3]);
      *(uint2*)&O[rowoff + grp*8] = pw;
    }
  }
}

extern "C" void kernel_launch(void* const* d_in, const int* in_sizes, int n_in,
                              void* d_out, int out_size, void* d_ws, size_t ws_size,
                              hipStream_t stream) {
  const float* X     = (const float*)d_in[0];
  const float* W_in  = (const float*)d_in[1];
  const float* b_in  = (const float*)d_in[2];
  const float* W_out = (const float*)d_in[3];
  const float* b_out = (const float*)d_in[4];
  float* out = (float*)d_out;

  char* ws = (char*)d_ws;
  const size_t MB = 1024 * 1024;
  const int M = 2 * SS;  // 4096

  if (ws_size >= 48 * MB) {
    short* Xb   = (short*)(ws);
    short* Wb1  = (short*)(ws + 8  * MB);
    short* Wb2  = (short*)(ws + 14 * MB);
    short* q_ws = (short*)(ws + 16 * MB);
    short* k_ws = (short*)(ws + 24 * MB);
    short* v_ws = (short*)(ws + 32 * MB);
    short* attn = (short*)(ws + 40 * MB);

    cvt_all<<<2048, 256, 0, stream>>>(X, W_in, W_out, Xb, Wb1, Wb2);
    gemm_qkv<<<dim3(24, 32), 256, 0, stream>>>(
        Xb, Wb1, b_in, q_ws, k_ws, v_ws, M, 3 * EE, EE);
    attn_kernel<<<dim3(512), 512, 0, stream>>>(q_ws, k_ws, v_ws, attn);
    gemm_out<<<dim3(8, 64), 256, 0, stream>>>(
        attn, Wb2, b_out, out, M, EE, EE);
  } else {
    short* q_ws = (short*)(ws);
    short* k_ws = (short*)(ws + 8  * MB);
    short* v_ws = (short*)(ws + 16 * MB);
    short* attn = (short*)(ws + 24 * MB);

    gemm_bt<1, float><<<dim3(24, 32), 256, 0, stream>>>(
        X, W_in, b_in, nullptr, q_ws, k_ws, v_ws, M, 3 * EE, EE);
    attn_kernel<<<dim3(512), 512, 0, stream>>>(q_ws, k_ws, v_ws, attn);
    gemm_bt<0, short><<<dim3(8, 32), 256, 0, stream>>>(
        attn, W_out, b_out, out, nullptr, nullptr, nullptr, M, EE, EE);
  }
}